// Round 3
// baseline (155.257 us; speedup 1.0000x reference)
//
#include <hip/hip_runtime.h>

#define FDIM 512

// ---------------- ws layout (floats) ----------------
#define R_OFF      0                    // r[256][512]
#define C_OFF      131072               // c[256][512]
#define S_OFF      262144               // s[256]
#define CP_OFF     262400               // c_part[256][8][512]
#define WS_FLOATS  (262400 + 256*8*512)

__device__ __forceinline__ float4 ld4(const float* p) { return *(const float4*)p; }

// ======================= K2: p, r, c-partials =======================
// grid: 256 batches x 8 slabs (64 rows). block: 512 threads (8 waves).
__global__ __launch_bounds__(512)
void k2_rc(const float* __restrict__ mu,
           const float* __restrict__ Sigma,
           float* __restrict__ p_out,    // d_out p section
           float* __restrict__ ws) {
    const int bid  = blockIdx.x;
    const int b    = bid >> 3;
    const int slab = bid & 7;
    const int t = threadIdx.x;
    const int w = t >> 6;
    const int l = t & 63;

    __shared__ __align__(16) float p_lds[FDIM];
    __shared__ __align__(16) float cred[8][FDIM];
    __shared__ float red[8];
    __shared__ float sc[1];

    // --- softmax p[b,:] (recomputed per slab-block; register-cheap) ---
    float x = mu[(size_t)b * FDIM + t];
    float m = x;
    #pragma unroll
    for (int off = 32; off >= 1; off >>= 1) m = fmaxf(m, __shfl_xor(m, off));
    if (l == 0) red[w] = m;
    __syncthreads();
    if (t == 0) {
        float mm = red[0];
        for (int j = 1; j < 8; ++j) mm = fmaxf(mm, red[j]);
        sc[0] = mm;
    }
    __syncthreads();
    const float mx = sc[0];
    float e = __expf(x - mx);
    float ssum = e;
    #pragma unroll
    for (int off = 32; off >= 1; off >>= 1) ssum += __shfl_xor(ssum, off);
    if (l == 0) red[w] = ssum;
    __syncthreads();
    if (t == 0) {
        float tt = 0.f;
        for (int j = 0; j < 8; ++j) tt += red[j];
        sc[0] = tt;
    }
    __syncthreads();
    const float pv = e / sc[0];
    p_lds[t] = pv;
    if (slab == 0) p_out[(size_t)b * FDIM + t] = pv;
    __syncthreads();

    const float4 p0 = ld4(&p_lds[4 * l]);
    const float4 p1 = ld4(&p_lds[256 + 4 * l]);

    // --- stream 8 rows per wave: r_i and c partial, no barriers ---
    const int i0 = slab * 64 + w * 8;
    const float* rowp = Sigma + (size_t)b * FDIM * FDIM + (size_t)i0 * FDIM + 4 * l;
    float* r_ws = ws + R_OFF + (size_t)b * FDIM;

    float4 c0 = make_float4(0.f, 0.f, 0.f, 0.f);
    float4 c1 = make_float4(0.f, 0.f, 0.f, 0.f);

    float4 a0 = ld4(rowp);
    float4 a1 = ld4(rowp + 256);
    #pragma unroll
    for (int q = 0; q < 8; ++q) {
        float4 n0, n1;
        if (q < 7) { n0 = ld4(rowp + (q + 1) * FDIM); n1 = ld4(rowp + (q + 1) * FDIM + 256); }
        const int i = i0 + q;
        const float pi = p_lds[i];
        float dot = a0.x * p0.x + a0.y * p0.y + a0.z * p0.z + a0.w * p0.w
                  + a1.x * p1.x + a1.y * p1.y + a1.z * p1.z + a1.w * p1.w;
        #pragma unroll
        for (int off = 32; off >= 1; off >>= 1) dot += __shfl_xor(dot, off);
        if (l == 0) r_ws[i] = dot;
        c0.x += pi * a0.x; c0.y += pi * a0.y; c0.z += pi * a0.z; c0.w += pi * a0.w;
        c1.x += pi * a1.x; c1.y += pi * a1.y; c1.z += pi * a1.z; c1.w += pi * a1.w;
        if (q < 7) { a0 = n0; a1 = n1; }
    }

    // --- block reduce c partials (one barrier, outside hot loop) ---
    *(float4*)&cred[w][4 * l] = c0;
    *(float4*)&cred[w][256 + 4 * l] = c1;
    __syncthreads();
    float cc = 0.f;
    #pragma unroll
    for (int j = 0; j < 8; ++j) cc += cred[j][t];
    ws[CP_OFF + ((size_t)b * 8 + slab) * FDIM + t] = cc;
}

// ======================= K2b: c reduce + s =======================
// grid: 256 blocks x 512 threads.
__global__ __launch_bounds__(512)
void k2b_cs(const float* __restrict__ p_out, float* __restrict__ ws) {
    const int b = blockIdx.x;
    const int t = threadIdx.x;
    const int w = t >> 6;
    const int l = t & 63;
    __shared__ float red[8];

    float cc = 0.f;
    #pragma unroll
    for (int j = 0; j < 8; ++j)
        cc += ws[CP_OFF + ((size_t)b * 8 + j) * FDIM + t];
    ws[C_OFF + (size_t)b * FDIM + t] = cc;

    float sv = p_out[(size_t)b * FDIM + t] * ws[R_OFF + (size_t)b * FDIM + t];
    #pragma unroll
    for (int off = 32; off >= 1; off >>= 1) sv += __shfl_xor(sv, off);
    if (l == 0) red[w] = sv;
    __syncthreads();
    if (t == 0) {
        float tt = 0.f;
        for (int j = 0; j < 8; ++j) tt += red[j];
        ws[S_OFF + b] = tt;
    }
}

// ======================= K3: output stream =======================
// grid: 256 batches x 16 slabs (32 rows), REVERSED for L3 reuse.
// block: 256 threads (4 waves), wave handles 8 rows. No barriers.
__global__ __launch_bounds__(256)
void k3_out(const float* __restrict__ Sigma,
            const float* __restrict__ p_out,
            const float* __restrict__ ws,
            float* __restrict__ S_out) {
    const int bid  = (int)gridDim.x - 1 - (int)blockIdx.x;   // reverse order
    const int b    = bid >> 4;
    const int slab = bid & 15;
    const int t = threadIdx.x;
    const int w = t >> 6;
    const int l = t & 63;

    const float* pb = p_out + (size_t)b * FDIM;
    const float* cb = ws + C_OFF + (size_t)b * FDIM;
    const float* rb = ws + R_OFF + (size_t)b * FDIM;
    const float  s  = ws[S_OFF + b];

    const float4 p0 = ld4(&pb[4 * l]);
    const float4 p1 = ld4(&pb[256 + 4 * l]);
    const float4 c0 = ld4(&cb[4 * l]);
    const float4 c1 = ld4(&cb[256 + 4 * l]);

    const int i0 = slab * 32 + w * 8;
    const float* rowp = Sigma + (size_t)b * FDIM * FDIM + (size_t)i0 * FDIM + 4 * l;
    float* orow       = S_out + (size_t)b * FDIM * FDIM + (size_t)i0 * FDIM + 4 * l;

    float4 a0 = ld4(rowp);
    float4 a1 = ld4(rowp + 256);
    float pi = pb[i0];
    float ri = rb[i0];
    #pragma unroll
    for (int q = 0; q < 8; ++q) {
        float4 n0, n1; float npi, nri;
        if (q < 7) {
            n0 = ld4(rowp + (q + 1) * FDIM);
            n1 = ld4(rowp + (q + 1) * FDIM + 256);
            npi = pb[i0 + q + 1];
            nri = rb[i0 + q + 1];
        }
        const float f = s - ri;
        float4 o0, o1;
        o0.x = pi * p0.x * (a0.x + (f - c0.x));
        o0.y = pi * p0.y * (a0.y + (f - c0.y));
        o0.z = pi * p0.z * (a0.z + (f - c0.z));
        o0.w = pi * p0.w * (a0.w + (f - c0.w));
        o1.x = pi * p1.x * (a1.x + (f - c1.x));
        o1.y = pi * p1.y * (a1.y + (f - c1.y));
        o1.z = pi * p1.z * (a1.z + (f - c1.z));
        o1.w = pi * p1.w * (a1.w + (f - c1.w));
        *(float4*)(orow + q * FDIM) = o0;
        *(float4*)(orow + q * FDIM + 256) = o1;
        if (q < 7) { a0 = n0; a1 = n1; pi = npi; ri = nri; }
    }
}

// ======================= fallback (round-2 fused) =======================
#define CHUNK 32
#define NCH 16
#define WAITVM4() asm volatile("s_waitcnt vmcnt(4)" ::: "memory")
#define WAITVM0() asm volatile("s_waitcnt vmcnt(0)" ::: "memory")
#define WAITLGKM0() asm volatile("s_waitcnt lgkmcnt(0)" ::: "memory")
#define BAR() __builtin_amdgcn_s_barrier()

__device__ __forceinline__ void gld_lds16(const float* g, float* l) {
    __builtin_amdgcn_global_load_lds(
        (const __attribute__((address_space(1))) void*)g,
        (__attribute__((address_space(3))) void*)l, 16, 0, 0);
}
__device__ __forceinline__ void stage_chunk(const float* Sb, int ch, float* buf,
                                            int w, int l) {
    const float* g = Sb + (size_t)(ch * CHUNK + w * 2) * FDIM + l * 4;
    float* d = buf + (w * 2) * FDIM;
    gld_lds16(g, d); gld_lds16(g + 256, d + 256);
    gld_lds16(g + 512, d + 512); gld_lds16(g + 768, d + 768);
}

__global__ __launch_bounds__(1024, 1)
void rvsoftmax_fused(const float* __restrict__ mu, const float* __restrict__ Sigma,
                     float* __restrict__ p_out, float* __restrict__ S_out) {
    const int b = blockIdx.x, t = threadIdx.x, w = t >> 6, l = t & 63;
    __shared__ __align__(16) float bufA[CHUNK * FDIM];
    __shared__ __align__(16) float bufB[CHUNK * FDIM];
    __shared__ __align__(16) float p_lds[FDIM];
    __shared__ __align__(16) float r_lds[FDIM];
    __shared__ __align__(16) float c_lds[FDIM];
    __shared__ float red[16]; __shared__ float sc[2];
    const float* Sb = Sigma + (size_t)b * FDIM * FDIM;
    stage_chunk(Sb, 0, bufA, w, l);
    float x = (t < FDIM) ? mu[(size_t)b * FDIM + t] : -__builtin_inff();
    float m = x;
    #pragma unroll
    for (int off = 32; off >= 1; off >>= 1) m = fmaxf(m, __shfl_xor(m, off));
    if (l == 0) red[w] = m;
    __syncthreads();
    if (t == 0) { float mm = red[0]; for (int j = 1; j < 16; ++j) mm = fmaxf(mm, red[j]); sc[0] = mm; }
    __syncthreads();
    const float mx = sc[0];
    float e = (t < FDIM) ? __expf(x - mx) : 0.f;
    float ssum = e;
    #pragma unroll
    for (int off = 32; off >= 1; off >>= 1) ssum += __shfl_xor(ssum, off);
    if (l == 0) red[w] = ssum;
    __syncthreads();
    if (t == 0) { float tt = 0.f; for (int j = 0; j < 16; ++j) tt += red[j]; sc[0] = tt; }
    __syncthreads();
    const float inv = 1.0f / sc[0];
    if (t < FDIM) { float pv = e * inv; p_lds[t] = pv; p_out[(size_t)b * FDIM + t] = pv; }
    __syncthreads();
    const float4 p0 = ld4(&p_lds[4 * l]);
    const float4 p1 = ld4(&p_lds[256 + 4 * l]);
    float4 c0 = make_float4(0.f, 0.f, 0.f, 0.f), c1 = make_float4(0.f, 0.f, 0.f, 0.f);
    for (int ch = 0; ch < NCH; ++ch) {
        float* cur = (ch & 1) ? bufB : bufA;
        float* nxt = (ch & 1) ? bufA : bufB;
        if (ch + 1 < NCH) { stage_chunk(Sb, ch + 1, nxt, w, l); WAITVM4(); } else { WAITVM0(); }
        BAR();
        #pragma unroll
        for (int q = 0; q < 2; ++q) {
            const int i = ch * CHUNK + w * 2 + q;
            const float* row = cur + (w * 2 + q) * FDIM;
            const float4 a0 = ld4(&row[4 * l]); const float4 a1 = ld4(&row[256 + 4 * l]);
            const float pi = p_lds[i];
            float dot = a0.x * p0.x + a0.y * p0.y + a0.z * p0.z + a0.w * p0.w
                      + a1.x * p1.x + a1.y * p1.y + a1.z * p1.z + a1.w * p1.w;
            #pragma unroll
            for (int off = 32; off >= 1; off >>= 1) dot += __shfl_xor(dot, off);
            if (l == 0) r_lds[i] = dot;
            c0.x += pi * a0.x; c0.y += pi * a0.y; c0.z += pi * a0.z; c0.w += pi * a0.w;
            c1.x += pi * a1.x; c1.y += pi * a1.y; c1.z += pi * a1.z; c1.w += pi * a1.w;
        }
        WAITLGKM0(); BAR();
    }
    *(float4*)&bufA[w * FDIM + 4 * l] = c0;
    *(float4*)&bufA[w * FDIM + 256 + 4 * l] = c1;
    __syncthreads();
    if (t < FDIM) {
        float cc = 0.f;
        #pragma unroll
        for (int j = 0; j < 16; ++j) cc += bufA[j * FDIM + t];
        c_lds[t] = cc;
    }
    float sv = (t < FDIM) ? p_lds[t] * r_lds[t] : 0.f;
    #pragma unroll
    for (int off = 32; off >= 1; off >>= 1) sv += __shfl_xor(sv, off);
    if (l == 0) red[w] = sv;
    __syncthreads();
    if (t == 0) { float tt = 0.f; for (int j = 0; j < 16; ++j) tt += red[j]; sc[1] = tt; }
    __syncthreads();
    const float s = sc[1];
    const float4 cc0 = ld4(&c_lds[4 * l]); const float4 cc1 = ld4(&c_lds[256 + 4 * l]);
    float* Ob = S_out + (size_t)b * FDIM * FDIM;
    stage_chunk(Sb, NCH - 1, bufA, w, l);
    for (int it = 0; it < NCH; ++it) {
        const int ch = NCH - 1 - it;
        float* cur = (it & 1) ? bufB : bufA;
        float* nxt = (it & 1) ? bufA : bufB;
        if (it + 1 < NCH) stage_chunk(Sb, ch - 1, nxt, w, l);
        WAITVM4(); BAR();
        #pragma unroll
        for (int q = 0; q < 2; ++q) {
            const int i = ch * CHUNK + w * 2 + q;
            const float* row = cur + (w * 2 + q) * FDIM;
            const float4 a0 = ld4(&row[4 * l]); const float4 a1 = ld4(&row[256 + 4 * l]);
            const float pi = p_lds[i];
            const float f = s - r_lds[i];
            float4 o0, o1;
            o0.x = pi * p0.x * (a0.x + (f - cc0.x)); o0.y = pi * p0.y * (a0.y + (f - cc0.y));
            o0.z = pi * p0.z * (a0.z + (f - cc0.z)); o0.w = pi * p0.w * (a0.w + (f - cc0.w));
            o1.x = pi * p1.x * (a1.x + (f - cc1.x)); o1.y = pi * p1.y * (a1.y + (f - cc1.y));
            o1.z = pi * p1.z * (a1.z + (f - cc1.z)); o1.w = pi * p1.w * (a1.w + (f - cc1.w));
            float* orow = S_out + (size_t)b * FDIM * FDIM + (size_t)i * FDIM;
            *(float4*)&orow[4 * l] = o0; *(float4*)&orow[256 + 4 * l] = o1;
        }
        WAITLGKM0(); BAR();
    }
    (void)Ob;
}

extern "C" void kernel_launch(void* const* d_in, const int* in_sizes, int n_in,
                              void* d_out, int out_size, void* d_ws, size_t ws_size,
                              hipStream_t stream) {
    const float* mu    = (const float*)d_in[0];
    const float* Sigma = (const float*)d_in[1];
    float* p_out = (float*)d_out;
    float* S_out = (float*)d_out + (size_t)256 * 512;

    if (ws_size >= (size_t)WS_FLOATS * sizeof(float)) {
        float* ws = (float*)d_ws;
        hipLaunchKernelGGL(k2_rc,  dim3(2048), dim3(512), 0, stream, mu, Sigma, p_out, ws);
        hipLaunchKernelGGL(k2b_cs, dim3(256),  dim3(512), 0, stream, p_out, ws);
        hipLaunchKernelGGL(k3_out, dim3(4096), dim3(256), 0, stream, Sigma, p_out, ws, S_out);
    } else {
        hipLaunchKernelGGL(rvsoftmax_fused, dim3(256), dim3(1024), 0, stream,
                           mu, Sigma, p_out, S_out);
    }
}